// Round 1
// baseline (233.664 us; speedup 1.0000x reference)
//
#include <hip/hip_runtime.h>
#include <hip/hip_fp16.h>
#include <cstdint>
#include <cstddef>

#define NHEAD 16
#define HDIM  64
#define HID   1024

using f16x8 = __attribute__((ext_vector_type(8))) _Float16;
using f32x4 = __attribute__((ext_vector_type(4))) float;

typedef const __attribute__((address_space(1))) unsigned int* gq_t;
typedef __attribute__((address_space(3))) unsigned int* lq_t;

// ---------------------------------------------------------------- converters
__global__ void cvt_f32_f16(const float* __restrict__ in, _Float16* __restrict__ out, int n8) {
    for (int i = blockIdx.x * blockDim.x + threadIdx.x; i < n8; i += gridDim.x * blockDim.x) {
        const float4* p = (const float4*)(in + (size_t)i * 8);
        float4 a = p[0], b = p[1];
        f16x8 o;
        o[0] = (_Float16)a.x; o[1] = (_Float16)a.y; o[2] = (_Float16)a.z; o[3] = (_Float16)a.w;
        o[4] = (_Float16)b.x; o[5] = (_Float16)b.y; o[6] = (_Float16)b.z; o[7] = (_Float16)b.w;
        *(f16x8*)(out + (size_t)i * 8) = o;
    }
}

// ------------------------------------------------------------------- GEMM
// C[M][N] = A[M][K] @ B[N][K]^T + bias[N]
// 128x128 tile, 4 waves (2x2), BK=64, global_load_lds staging,
// XOR slot-swizzle (slot ^= row&7) to spread LDS banks on ds_read_b128.
template <typename OutT>
__global__ __launch_bounds__(256, 2)
void gemm_bt(const _Float16* __restrict__ A, const _Float16* __restrict__ Bw,
             const float* __restrict__ bias, OutT* __restrict__ C,
             int M, int N, int K)
{
    __shared__ _Float16 As[128 * 64];
    __shared__ _Float16 Bs[128 * 64];

    const int tid  = threadIdx.x;
    const int lane = tid & 63;
    const int wid  = tid >> 6;
    const int wm   = wid >> 1;   // 0..1
    const int wn   = wid & 1;    // 0..1
    const int m0   = blockIdx.y * 128;
    const int n0   = blockIdx.x * 128;

    f32x4 acc[4][4] = {};

    const int r_in  = lane >> 3;       // 0..7 row within wave's 8-row strip
    const int s_lds = lane & 7;        // 0..7 16B slot within row

    for (int k0 = 0; k0 < K; k0 += 64) {
        // ---- stage A,B tiles (128 rows x 64 f16 = 16 KiB each), 4 issues per matrix
        #pragma unroll
        for (int j = 0; j < 4; ++j) {
            const int rbase = j * 32 + wid * 8;       // wave-uniform
            const int r     = rbase + r_in;
            const int s_g   = s_lds ^ (r & 7);        // pre-swizzled global source
            const _Float16* ga = A  + (size_t)(m0 + r) * K + k0 + s_g * 8;
            const _Float16* gb = Bw + (size_t)(n0 + r) * K + k0 + s_g * 8;
            __builtin_amdgcn_global_load_lds((gq_t)(const void*)ga,
                                             (lq_t)(void*)(As + rbase * 64), 16, 0, 0);
            __builtin_amdgcn_global_load_lds((gq_t)(const void*)gb,
                                             (lq_t)(void*)(Bs + rbase * 64), 16, 0, 0);
        }
        __syncthreads();

        // ---- compute: 2 K-steps of 32, 16 MFMA each
        const int g = lane >> 4;              // k-group 0..3
        #pragma unroll
        for (int kk = 0; kk < 2; ++kk) {
            f16x8 af[4], bf[4];
            #pragma unroll
            for (int mi = 0; mi < 4; ++mi) {
                const int row  = wm * 64 + mi * 16 + (lane & 15);
                const int slot = (kk * 4 + g) ^ (row & 7);
                af[mi] = *(const f16x8*)&As[row * 64 + slot * 8];
            }
            #pragma unroll
            for (int ni = 0; ni < 4; ++ni) {
                const int row  = wn * 64 + ni * 16 + (lane & 15);
                const int slot = (kk * 4 + g) ^ (row & 7);
                bf[ni] = *(const f16x8*)&Bs[row * 64 + slot * 8];
            }
            #pragma unroll
            for (int mi = 0; mi < 4; ++mi)
                #pragma unroll
                for (int ni = 0; ni < 4; ++ni)
                    acc[mi][ni] = __builtin_amdgcn_mfma_f32_16x16x32_f16(
                        af[mi], bf[ni], acc[mi][ni], 0, 0, 0);
        }
        __syncthreads();
    }

    // ---- epilogue: bias + store. D: col = lane&15, row = (lane>>4)*4 + q
    #pragma unroll
    for (int ni = 0; ni < 4; ++ni) {
        const int col = n0 + wn * 64 + ni * 16 + (lane & 15);
        const float bv = bias[col];
        #pragma unroll
        for (int mi = 0; mi < 4; ++mi) {
            const int rowb = m0 + wm * 64 + mi * 16 + (lane >> 4) * 4;
            #pragma unroll
            for (int q = 0; q < 4; ++q) {
                const float val = acc[mi][ni][q] + bv;
                C[(size_t)(rowb + q) * N + col] = (OutT)val;
            }
        }
    }
}

// --------------------------------------------------------------- attention
// Per token: q,k,v in [16][64]; scores = (q*scale)@k^T / 8; softmax over t;
// out = attn @ v.  8 tokens/block, 128 threads: thread = (token, head-row h).
__global__ __launch_bounds__(128, 2)
void attn_kernel(const _Float16* __restrict__ qkv, const float* __restrict__ scale,
                 _Float16* __restrict__ out)
{
    __shared__ _Float16 kv[8][2048];   // per token: k[0..1024), v[1024..2048)
    __shared__ float sc[64];

    const int tid  = threadIdx.x;
    const int tok0 = blockIdx.x * 8;

    if (tid < 64) sc[tid] = scale[tid];

    // cooperative coalesced load of k,v for 8 tokens
    #pragma unroll
    for (int it = 0; it < 16; ++it) {
        const int vid = tid + it * 128;        // 0..2047 (vec8 units)
        const int tok = vid >> 8;              // 0..7
        const int ofs = (vid & 255) * 8;       // 0..2040
        *(f16x8*)&kv[tok][ofs] =
            *(const f16x8*)&qkv[(size_t)(tok0 + tok) * 3072 + 1024 + ofs];
    }
    __syncthreads();

    const int tok = tid >> 4;
    const int h   = tid & 15;
    const size_t qbase = (size_t)(tok0 + tok) * 3072 + h * 64;

    float q[64];
    #pragma unroll
    for (int d0 = 0; d0 < 64; d0 += 8) {
        f16x8 qv = *(const f16x8*)&qkv[qbase + d0];
        #pragma unroll
        for (int j = 0; j < 8; ++j) q[d0 + j] = (float)qv[j] * sc[d0 + j];
    }

    float s[16];
    #pragma unroll
    for (int t = 0; t < 16; ++t) {
        float a = 0.f;
        #pragma unroll
        for (int d0 = 0; d0 < 64; d0 += 8) {
            f16x8 kvv = *(const f16x8*)&kv[tok][t * 64 + d0];
            #pragma unroll
            for (int j = 0; j < 8; ++j) a += q[d0 + j] * (float)kvv[j];
        }
        s[t] = a * 0.125f;
    }

    float mx = s[0];
    #pragma unroll
    for (int t = 1; t < 16; ++t) mx = fmaxf(mx, s[t]);
    float sum = 0.f;
    #pragma unroll
    for (int t = 0; t < 16; ++t) { s[t] = __expf(s[t] - mx); sum += s[t]; }
    const float inv = 1.f / sum;

    float o[64] = {};
    #pragma unroll
    for (int t = 0; t < 16; ++t) {
        const float a = s[t] * inv;
        #pragma unroll
        for (int d0 = 0; d0 < 64; d0 += 8) {
            f16x8 vv = *(const f16x8*)&kv[tok][1024 + t * 64 + d0];
            #pragma unroll
            for (int j = 0; j < 8; ++j) o[d0 + j] += a * (float)vv[j];
        }
    }

    #pragma unroll
    for (int d0 = 0; d0 < 64; d0 += 8) {
        f16x8 ov;
        #pragma unroll
        for (int j = 0; j < 8; ++j) ov[j] = (_Float16)o[d0 + j];
        *(f16x8*)&out[(size_t)(tok0 + tok) * 1024 + h * 64 + d0] = ov;
    }
}

// ----------------------------------------------------------------- launcher
extern "C" void kernel_launch(void* const* d_in, const int* in_sizes, int n_in,
                              void* d_out, int out_size, void* d_ws, size_t ws_size,
                              hipStream_t stream)
{
    const float* x     = (const float*)d_in[0];
    const float* Wq    = (const float*)d_in[1];
    const float* bq    = (const float*)d_in[2];
    const float* Wk    = (const float*)d_in[3];
    const float* bk    = (const float*)d_in[4];
    const float* Wv    = (const float*)d_in[5];
    const float* bv    = (const float*)d_in[6];
    const float* Wo    = (const float*)d_in[7];
    const float* bo    = (const float*)d_in[8];
    const float* scale = (const float*)d_in[9];
    float* out = (float*)d_out;

    const int M = in_sizes[0] / HID;   // 16384 tokens

    // workspace layout (bytes):
    //  x16/attn16 : M*1024*2        (attn output reuses x16 after QKV GEMM)
    //  wqkv16     : 3072*1024*2
    //  wo16       : 1024*1024*2
    //  bqkv       : 3072*4
    //  qkv16      : M*3072*2
    char* ws = (char*)d_ws;
    _Float16* x16    = (_Float16*)ws;
    _Float16* attn16 = x16;
    _Float16* wqkv16 = (_Float16*)(ws + (size_t)M * HID * 2);
    _Float16* wo16   = wqkv16 + (size_t)3 * HID * HID;
    float*    bqkv   = (float*)(wo16 + (size_t)HID * HID);
    _Float16* qkv16  = (_Float16*)((char*)bqkv + 3 * HID * 4);

    hipMemcpyAsync(bqkv,            bq, HID * 4, hipMemcpyDeviceToDevice, stream);
    hipMemcpyAsync(bqkv + HID,      bk, HID * 4, hipMemcpyDeviceToDevice, stream);
    hipMemcpyAsync(bqkv + 2 * HID,  bv, HID * 4, hipMemcpyDeviceToDevice, stream);

    cvt_f32_f16<<<4096, 256, 0, stream>>>(x,  x16,                 M * HID / 8);
    cvt_f32_f16<<<1024, 256, 0, stream>>>(Wq, wqkv16,              HID * HID / 8);
    cvt_f32_f16<<<1024, 256, 0, stream>>>(Wk, wqkv16 + HID * HID,  HID * HID / 8);
    cvt_f32_f16<<<1024, 256, 0, stream>>>(Wv, wqkv16 + 2*HID*HID,  HID * HID / 8);
    cvt_f32_f16<<<1024, 256, 0, stream>>>(Wo, wo16,                HID * HID / 8);

    // QKV GEMM: [M,1024] @ [3072,1024]^T -> qkv16 [M,3072] (f16)
    gemm_bt<_Float16><<<dim3(3 * HID / 128, M / 128), 256, 0, stream>>>(
        x16, wqkv16, bqkv, qkv16, M, 3 * HID, HID);

    // per-token head-mix attention -> attn16 [M,1024] (f16)
    attn_kernel<<<M / 8, 128, 0, stream>>>(qkv16, scale, attn16);

    // output GEMM: [M,1024] @ [1024,1024]^T + bo -> out (f32)
    gemm_bt<float><<<dim3(HID / 128, M / 128), 256, 0, stream>>>(
        attn16, wo16, bo, out, M, HID, HID);
}